// Round 5
// baseline (326.344 us; speedup 1.0000x reference)
//
#include <hip/hip_runtime.h>

#define NB_ 16   // batch
#define S_ 512
#define D_ 768
#define H_ 12
#define DH_ 64
#define QT_ 64   // flash q-tile
#define KT_ 128  // flash k-tile

typedef __attribute__((ext_vector_type(8))) short bf16x8;
typedef __attribute__((ext_vector_type(4))) float f32x4;
typedef unsigned short ushort_t;

__device__ __forceinline__ unsigned short f2bf(float f){
  unsigned int u = __float_as_uint(f);
  u += 0x7fffu + ((u >> 16) & 1u);   // round-to-nearest-even
  return (unsigned short)(u >> 16);
}
__device__ __forceinline__ float bf2f(unsigned short s){
  return __uint_as_float(((unsigned int)s) << 16);
}
// async global->LDS, 16B per lane. LDS side must be uniform-base + lane*16,
// which holds because chunk index is linear in tid within each wave.
__device__ __forceinline__ void gld16(const ushort_t* g, ushort_t* l){
  __builtin_amdgcn_global_load_lds((const __attribute__((address_space(1))) unsigned int*)g,
                                   (__attribute__((address_space(3))) unsigned int*)l, 16, 0, 0);
}

// ---------------- fp32 -> bf16 bulk convert ----------------
__global__ __launch_bounds__(256) void k_f32_to_bf16(const float* __restrict__ in,
                                                     ushort_t* __restrict__ out, int n4){
  int i = blockIdx.x * 256 + threadIdx.x;
  if (i < n4){
    float4 f = ((const float4*)in)[i];
    unsigned int lo = (unsigned int)f2bf(f.x) | ((unsigned int)f2bf(f.y) << 16);
    unsigned int hi = (unsigned int)f2bf(f.z) | ((unsigned int)f2bf(f.w) << 16);
    ((uint2*)out)[i] = make_uint2(lo, hi);
  }
}

// ---------------- weight transpose fp32[K][N] -> bf16[N][K] ----------------
__global__ __launch_bounds__(256) void k_wtrans(const float* __restrict__ W0, const float* __restrict__ W1,
                                                const float* __restrict__ W2, const float* __restrict__ W3,
                                                ushort_t* __restrict__ dst){
  const float* W = (blockIdx.z == 0) ? W0 : (blockIdx.z == 1) ? W1 : (blockIdx.z == 2) ? W2 : W3;
  ushort_t* o = dst + (size_t)blockIdx.z * D_ * D_;
  __shared__ float t[32][33];
  int j = threadIdx.x & 31, i0 = threadIdx.x >> 5;
  int kb = blockIdx.y * 32, nb = blockIdx.x * 32;
#pragma unroll
  for (int r = 0; r < 4; r++){
    int i = i0 + r * 8;
    t[i][j] = W[(size_t)(kb + i) * D_ + nb + j];
  }
  __syncthreads();
#pragma unroll
  for (int r = 0; r < 4; r++){
    int i = i0 + r * 8;
    o[(size_t)(nb + i) * D_ + kb + j] = f2bf(t[j][i]);
  }
}

// ---------------- concat bq|bk|bv -> [2304] ----------------
__global__ __launch_bounds__(256) void k_bias3(const float* __restrict__ b0, const float* __restrict__ b1,
                                               const float* __restrict__ b2, float* __restrict__ o){
  int i = blockIdx.x * 256 + threadIdx.x;
  if (i < 3 * D_){
    float v = (i < D_) ? b0[i] : (i < 2 * D_) ? b1[i - D_] : b2[i - 2 * D_];
    o[i] = v;
  }
}

// ---------------- pooled gate, stage 1 ----------------
__global__ __launch_bounds__(256) void k_pool1(const float* __restrict__ hs, const float* __restrict__ mask,
                                               float* __restrict__ partial, float* __restrict__ pcnt){
  int chunk = blockIdx.x, b = blockIdx.y, tid = threadIdx.x;
  const float* mrow = mask + b * S_ + chunk * 64;
  const float* base = hs + ((size_t)b * S_ + chunk * 64) * D_;
  float a0 = 0.f, a1 = 0.f, a2 = 0.f, cnt = 0.f;
#pragma unroll 4
  for (int s = 0; s < 64; s++){
    if (mrow[s] == 0.0f){
      const float* r = base + (size_t)s * D_;
      a0 += r[tid]; a1 += r[tid + 256]; a2 += r[tid + 512];
      cnt += 1.0f;
    }
  }
  float* o = partial + (size_t)(b * 8 + chunk) * D_;
  o[tid] = a0; o[tid + 256] = a1; o[tid + 512] = a2;
  if (tid == 0) pcnt[b * 8 + chunk] = cnt;
}

// ---------------- pooled gate, stage 2 ----------------
__global__ __launch_bounds__(256) void k_pool2(const float* __restrict__ partial, const float* __restrict__ pcnt,
                                               const float* __restrict__ Wg, const float* __restrict__ bg,
                                               float* __restrict__ gate){
  int b = blockIdx.x, tid = threadIdx.x;
  __shared__ float red[256];
  __shared__ float hp[768];
  float a0 = 0.f, a1 = 0.f, a2 = 0.f;
#pragma unroll
  for (int c = 0; c < 8; c++){
    const float* p = partial + (size_t)(b * 8 + c) * D_;
    a0 += p[tid]; a1 += p[tid + 256]; a2 += p[tid + 512];
  }
  float denom = 0.f;
#pragma unroll
  for (int c = 0; c < 8; c++) denom += pcnt[b * 8 + c];
  float inv = 1.0f / fmaxf(denom, 1.0f);
  hp[tid] = a0 * inv; hp[tid + 256] = a1 * inv; hp[tid + 512] = a2 * inv;
  __syncthreads();
  float p0 = 0.f, p1 = 0.f;
  for (int d = tid; d < D_; d += 256){ p0 += hp[d] * Wg[d * 2]; p1 += hp[d] * Wg[d * 2 + 1]; }
  red[tid] = p0; __syncthreads();
  for (int o = 128; o > 0; o >>= 1){ if (tid < o) red[tid] += red[tid + o]; __syncthreads(); }
  float z0 = red[0]; __syncthreads();
  red[tid] = p1; __syncthreads();
  for (int o = 128; o > 0; o >>= 1){ if (tid < o) red[tid] += red[tid + o]; __syncthreads(); }
  float z1 = red[0];
  if (tid == 0){
    z0 = (z0 + bg[0]) * 0.5f; z1 = (z1 + bg[1]) * 0.5f;
    float m = fmaxf(z0, z1);
    float e0 = __expf(z0 - m), e1 = __expf(z1 - m);
    float ssum = e0 + e1;
    gate[b * 2] = e0 / ssum; gate[b * 2 + 1] = e1 / ssum;
  }
}

// ---------------- BT GEMM (128x128 tile, swizzled LDS, global_load_lds) ----------------
// C[z] = act(alpha*A[z]*B[z]^T + bias [+ resid]); A:[M][K] lda, B:[N][K] ldb.
// LDS layout: 16B chunk of logical (row, kchunk c) stored at position row*4 + (c ^ ((row>>1)&3)).
// Staging stays lane-linear (gld16-legal); fragment reads hit all 32 banks (no conflicts).
// AFP32: A operand is fp32 in global, converted to bf16 during staging (VGPR path).
template<int OUTBF16, int RELU, int RESID, int AFP32>
__global__ __launch_bounds__(256) void k_gemm_bt(
    const void* __restrict__ Ap, long sA, int lda,
    const ushort_t* __restrict__ Bm, long sB, int ldb,
    void* __restrict__ Cp, long sC, int ldc,
    const float* __restrict__ bias,
    const float* __restrict__ resid, float alpha, int K)
{
  __shared__ ushort_t As[128 * 32];
  __shared__ ushort_t Bs[128 * 32];
  const int z = blockIdx.z;
  const ushort_t* Ab = AFP32 ? nullptr : ((const ushort_t*)Ap + (size_t)z * sA);
  const float*    Af = AFP32 ? ((const float*)Ap + (size_t)z * sA) : nullptr;
  const ushort_t* Bb = Bm + (size_t)z * sB;
  const long coff = (long)z * sC;
  const int tid = threadIdx.x;
  const int m0 = blockIdx.y * 128, n0 = blockIdx.x * 128;
  const int wid = tid >> 6, lane = tid & 63;
  const int quad = lane >> 4, l16 = lane & 15;
  const int wm = wid >> 1, wn = wid & 1;
  const int sw = (l16 >> 1) & 3;          // fragment-read swizzle (row-local)

  f32x4 acc[4][4];
#pragma unroll
  for (int i = 0; i < 4; i++)
#pragma unroll
    for (int j = 0; j < 4; j++) acc[i][j] = (f32x4){0.f, 0.f, 0.f, 0.f};

  for (int k0 = 0; k0 < K; k0 += 32){
#pragma unroll
    for (int c = 0; c < 2; c++){
      int idx = tid + c * 256;
      int row = idx >> 2, p = idx & 3;
      int cg = p ^ ((row >> 1) & 3);
      if (AFP32){
        const float* src = Af + (size_t)(m0 + row) * lda + k0 + cg * 8;
        float4 f0 = *(const float4*)src;
        float4 f1 = *(const float4*)(src + 4);
        uint4 pk;
        pk.x = (unsigned int)f2bf(f0.x) | ((unsigned int)f2bf(f0.y) << 16);
        pk.y = (unsigned int)f2bf(f0.z) | ((unsigned int)f2bf(f0.w) << 16);
        pk.z = (unsigned int)f2bf(f1.x) | ((unsigned int)f2bf(f1.y) << 16);
        pk.w = (unsigned int)f2bf(f1.z) | ((unsigned int)f2bf(f1.w) << 16);
        *(uint4*)(&As[idx * 8]) = pk;
      } else {
        gld16(Ab + (size_t)(m0 + row) * lda + k0 + cg * 8, &As[idx * 8]);
      }
    }
#pragma unroll
    for (int c = 0; c < 2; c++){
      int idx = tid + c * 256;
      int row = idx >> 2, p = idx & 3;
      int cg = p ^ ((row >> 1) & 3);
      gld16(Bb + (size_t)(n0 + row) * ldb + k0 + cg * 8, &Bs[idx * 8]);
    }
    __syncthreads();
    bf16x8 af[4], bfv[4];
#pragma unroll
    for (int mi = 0; mi < 4; mi++){
      int row = wm * 64 + mi * 16 + l16;
      af[mi] = *(const bf16x8*)(&As[(row * 4 + (quad ^ sw)) * 8]);
    }
#pragma unroll
    for (int ni = 0; ni < 4; ni++){
      int row = wn * 64 + ni * 16 + l16;
      bfv[ni] = *(const bf16x8*)(&Bs[(row * 4 + (quad ^ sw)) * 8]);
    }
#pragma unroll
    for (int mi = 0; mi < 4; mi++)
#pragma unroll
      for (int ni = 0; ni < 4; ni++)
        acc[mi][ni] = __builtin_amdgcn_mfma_f32_16x16x32_bf16(af[mi], bfv[ni], acc[mi][ni], 0, 0, 0);
    __syncthreads();
  }

#pragma unroll
  for (int mi = 0; mi < 4; mi++){
#pragma unroll
    for (int ni = 0; ni < 4; ni++){
      int col = n0 + wn * 64 + ni * 16 + l16;
      float bcol = bias ? bias[col] : 0.0f;
#pragma unroll
      for (int r = 0; r < 4; r++){
        int row = m0 + wm * 64 + mi * 16 + quad * 4 + r;
        float v = acc[mi][ni][r] * alpha + bcol;
        if (RELU) v = fmaxf(v, 0.0f);
        if (RESID) v += resid[(size_t)row * ldc + col];
        long idx = coff + (long)row * ldc + col;
        if (OUTBF16) ((ushort_t*)Cp)[idx] = f2bf(v);
        else         ((float*)Cp)[idx] = v;
      }
    }
  }
}

// ---------------- per-head V transpose: vt[z][dh][t] = v[b,t,(voff)+h*64+dh] ----------------
__global__ __launch_bounds__(256) void k_vtrans(const ushort_t* __restrict__ v, int ldv,
                                                ushort_t* __restrict__ vt){
  __shared__ ushort_t t[64][66];
  int st = blockIdx.x * 64; int z = blockIdx.y;
  int b = z / H_, h = z - b * H_;
  int tid = threadIdx.x;
  const ushort_t* src = v + ((size_t)b * S_ + st) * ldv + h * DH_;
#pragma unroll
  for (int rep = 0; rep < 8; rep++){
    int idx = rep * 256 + tid;
    int i = idx >> 5, u = idx & 31;
    unsigned int val = *(const unsigned int*)(src + (size_t)i * ldv + u * 2);
    *(unsigned int*)(&t[i][u * 2]) = val;
  }
  __syncthreads();
  ushort_t* dst = vt + (size_t)z * DH_ * S_ + st;
#pragma unroll
  for (int rep = 0; rep < 8; rep++){
    int idx = rep * 256 + tid;
    int d = idx >> 5, u2 = idx & 31;
    unsigned int val = (unsigned int)t[u2 * 2][d] | ((unsigned int)t[u2 * 2 + 1][d] << 16);
    *(unsigned int*)(dst + (size_t)d * S_ + u2 * 2) = val;
  }
}

// ---------------- fused flash attention with prior blend ----------------
// ctx[b,q,h*64+dh] = (g0/l_q) * sum_t exp(0.125*q.k + mask_t) * V[t,dh] + g1 * priorctx[b,q,h*64+dh]
__global__ __launch_bounds__(256) void k_flash(
    const ushort_t* __restrict__ qkv,      // [B*S][2304]; q at col 0, k at col 768
    const ushort_t* __restrict__ vt,       // [B*H][64][512]
    const ushort_t* __restrict__ priorctx, // [B*S][768] bf16
    const float* __restrict__ mask,        // [B][S]
    const float* __restrict__ gate,        // [B][2]
    ushort_t* __restrict__ ctx)            // [B*S][768]
{
  __shared__ ushort_t Qs[QT_ * 72];    // [q][dh], pad to 72
  __shared__ ushort_t Ks[KT_ * 72];    // [t][dh]
  __shared__ ushort_t Vs[DH_ * 136];   // [dh][t], pad to 136
  __shared__ ushort_t Ps[QT_ * 136];   // [q][t]
  __shared__ float rs[QT_];
  const int z = blockIdx.z, b = z / H_, h = z - b * H_;
  const int q0 = blockIdx.x * QT_;
  const int tid = threadIdx.x;
  const int wid = tid >> 6, lane = tid & 63, quad = lane >> 4, l16 = lane & 15;

  // stage Q tile (64 x 64)
#pragma unroll
  for (int i = 0; i < 2; i++){
    int c = tid + i * 256;
    int row = c >> 3, off = (c & 7) * 8;
    *(float4*)(&Qs[row * 72 + off]) =
      *(const float4*)(qkv + ((size_t)(b * S_ + q0 + row)) * 2304 + h * DH_ + off);
  }
  if (tid < QT_) rs[tid] = 0.f;

  f32x4 accv[4];
#pragma unroll
  for (int ni = 0; ni < 4; ni++) accv[ni] = (f32x4){0.f, 0.f, 0.f, 0.f};

  for (int t0 = 0; t0 < S_; t0 += KT_){
    // stage K tile (128 x 64) and V^T tile (64 x 128)
#pragma unroll
    for (int i = 0; i < 4; i++){
      int c = tid + i * 256;
      int row = c >> 3, off = (c & 7) * 8;
      *(float4*)(&Ks[row * 72 + off]) =
        *(const float4*)(qkv + ((size_t)(b * S_ + t0 + row)) * 2304 + D_ + h * DH_ + off);
    }
#pragma unroll
    for (int i = 0; i < 4; i++){
      int c = tid + i * 256;
      int row = c >> 4, off = (c & 15) * 8;
      *(float4*)(&Vs[row * 136 + off]) =
        *(const float4*)(vt + (size_t)z * (DH_ * S_) + (size_t)row * S_ + t0 + off);
    }
    __syncthreads();

    // S^T = K·Q^T : A = K tokens (m, 128), B = Q rows (n, 64), k-dim = dh (64)
    f32x4 accs[2][4];
#pragma unroll
    for (int mi = 0; mi < 2; mi++)
#pragma unroll
      for (int ni = 0; ni < 4; ni++) accs[mi][ni] = (f32x4){0.f, 0.f, 0.f, 0.f};
    bf16x8 ak[2][2], bq[4][2];
#pragma unroll
    for (int mi = 0; mi < 2; mi++)
#pragma unroll
      for (int ks = 0; ks < 2; ks++)
        ak[mi][ks] = *(const bf16x8*)(&Ks[(wid * 32 + mi * 16 + l16) * 72 + ks * 32 + quad * 8]);
#pragma unroll
    for (int ni = 0; ni < 4; ni++)
#pragma unroll
      for (int ks = 0; ks < 2; ks++)
        bq[ni][ks] = *(const bf16x8*)(&Qs[(ni * 16 + l16) * 72 + ks * 32 + quad * 8]);
#pragma unroll
    for (int mi = 0; mi < 2; mi++)
#pragma unroll
      for (int ni = 0; ni < 4; ni++){
        accs[mi][ni] = __builtin_amdgcn_mfma_f32_16x16x32_bf16(ak[mi][0], bq[ni][0], accs[mi][ni], 0, 0, 0);
        accs[mi][ni] = __builtin_amdgcn_mfma_f32_16x16x32_bf16(ak[mi][1], bq[ni][1], accs[mi][ni], 0, 0, 0);
      }

    // exp + pack into Ps[q][t] (lane holds 4 contiguous t for fixed q) + row sums
    float mv[2][4];
#pragma unroll
    for (int mi = 0; mi < 2; mi++)
#pragma unroll
      for (int r = 0; r < 4; r++)
        mv[mi][r] = mask[b * S_ + t0 + wid * 32 + mi * 16 + quad * 4 + r];
    float rowpart[4] = {0.f, 0.f, 0.f, 0.f};
#pragma unroll
    for (int mi = 0; mi < 2; mi++){
#pragma unroll
      for (int ni = 0; ni < 4; ni++){
        float e0 = __expf(accs[mi][ni][0] * 0.125f + mv[mi][0]);
        float e1 = __expf(accs[mi][ni][1] * 0.125f + mv[mi][1]);
        float e2 = __expf(accs[mi][ni][2] * 0.125f + mv[mi][2]);
        float e3 = __expf(accs[mi][ni][3] * 0.125f + mv[mi][3]);
        rowpart[ni] += (e0 + e1) + (e2 + e3);
        uint2 pk;
        pk.x = (unsigned int)f2bf(e0) | ((unsigned int)f2bf(e1) << 16);
        pk.y = (unsigned int)f2bf(e2) | ((unsigned int)f2bf(e3) << 16);
        *(uint2*)(&Ps[(ni * 16 + l16) * 136 + wid * 32 + mi * 16 + quad * 4]) = pk;
      }
    }
#pragma unroll
    for (int ni = 0; ni < 4; ni++){
      rowpart[ni] += __shfl_xor(rowpart[ni], 16);
      rowpart[ni] += __shfl_xor(rowpart[ni], 32);
    }
    if (lane < 16){
#pragma unroll
      for (int ni = 0; ni < 4; ni++) atomicAdd(&rs[ni * 16 + l16], rowpart[ni]);
    }
    __syncthreads();

    // PV: A = Ps (m = q, this wave's 16 rows), B = Vs (n = dh), k = t (128)
#pragma unroll
    for (int ks = 0; ks < 4; ks++){
      bf16x8 ap = *(const bf16x8*)(&Ps[(wid * 16 + l16) * 136 + ks * 32 + quad * 8]);
#pragma unroll
      for (int ni = 0; ni < 4; ni++){
        bf16x8 bv8 = *(const bf16x8*)(&Vs[(ni * 16 + l16) * 136 + ks * 32 + quad * 8]);
        accv[ni] = __builtin_amdgcn_mfma_f32_16x16x32_bf16(ap, bv8, accv[ni], 0, 0, 0);
      }
    }
    __syncthreads();
  }

  const float g0 = gate[b * 2], g1 = gate[b * 2 + 1];
#pragma unroll
  for (int ni = 0; ni < 4; ni++){
#pragma unroll
    for (int r = 0; r < 4; r++){
      int q = wid * 16 + quad * 4 + r;
      int dh = ni * 16 + l16;
      float scl = g0 / rs[q];
      size_t idx = ((size_t)(b * S_ + q0 + q)) * D_ + h * DH_ + dh;
      float v = accv[ni][r] * scl + g1 * bf2f(priorctx[idx]);
      ctx[idx] = f2bf(v);
    }
  }
}

// ---------------- in-place LayerNorm over D=768 ----------------
__global__ __launch_bounds__(256) void k_ln(float* __restrict__ out, const float* __restrict__ gamma,
                                            const float* __restrict__ beta){
  __shared__ float red[256];
  int row = blockIdx.x, tid = threadIdx.x;
  float* p = out + (size_t)row * D_;
  float x0 = p[tid], x1 = p[tid + 256], x2 = p[tid + 512];
  red[tid] = x0 + x1 + x2; __syncthreads();
  for (int o = 128; o > 0; o >>= 1){ if (tid < o) red[tid] += red[tid + o]; __syncthreads(); }
  float mu = red[0] * (1.0f / 768.0f);
  __syncthreads();
  float d0 = x0 - mu, d1 = x1 - mu, d2 = x2 - mu;
  red[tid] = d0 * d0 + d1 * d1 + d2 * d2; __syncthreads();
  for (int o = 128; o > 0; o >>= 1){ if (tid < o) red[tid] += red[tid + o]; __syncthreads(); }
  float rsv = rsqrtf(red[0] * (1.0f / 768.0f) + 1e-5f);
  p[tid]       = d0 * rsv * gamma[tid]       + beta[tid];
  p[tid + 256] = d1 * rsv * gamma[tid + 256] + beta[tid + 256];
  p[tid + 512] = d2 * rsv * gamma[tid + 512] + beta[tid + 512];
}

extern "C" void kernel_launch(void* const* d_in, const int* in_sizes, int n_in,
                              void* d_out, int out_size, void* d_ws, size_t ws_size,
                              hipStream_t stream){
  const float* hs    = (const float*)d_in[0];
  const float* mask  = (const float*)d_in[1];
  const float* prior = (const float*)d_in[2];
  const float* Wq = (const float*)d_in[3];  const float* bq = (const float*)d_in[4];
  const float* Wk = (const float*)d_in[5];  const float* bk = (const float*)d_in[6];
  const float* Wv = (const float*)d_in[7];  const float* bv = (const float*)d_in[8];
  const float* Wg = (const float*)d_in[9];  const float* bg = (const float*)d_in[10];
  const float* Wo = (const float*)d_in[11]; const float* bo = (const float*)d_in[12];
  const float* gamma = (const float*)d_in[13]; const float* beta = (const float*)d_in[14];
  float* out = (float*)d_out;

  size_t off = 0;
  auto alloc = [&](size_t bytes) -> char* {
    char* p = (char*)d_ws + off;
    off += (bytes + 255) & ~(size_t)255;
    return p;
  };
  const size_t HSD = (size_t)NB_ * S_ * D_;            // 6.29M elems
  ushort_t* hsb     = (ushort_t*)alloc(HSD * 2);
  ushort_t* qkvb    = (ushort_t*)alloc(HSD * 3 * 2);   // [B*S][2304]
  ushort_t* vtb     = (ushort_t*)alloc(HSD * 2);       // [B*H][64][512]
  ushort_t* wt      = (ushort_t*)alloc((size_t)4 * D_ * D_ * 2);
  ushort_t* priorctx= (ushort_t*)alloc(HSD * 2);
  ushort_t* ctx     = (ushort_t*)alloc(HSD * 2);
  float*    bqkv    = (float*)alloc((size_t)3 * D_ * 4);
  float*    gate    = (float*)alloc(256);
  float*    partial = (float*)alloc((size_t)NB_ * 8 * D_ * 4);
  float*    pcnt    = (float*)alloc((size_t)NB_ * 8 * 4);

  // 1. converts / packs
  k_f32_to_bf16<<<dim3((int)(HSD / 4 / 256)), 256, 0, stream>>>(hs, hsb, (int)(HSD / 4));
  k_wtrans<<<dim3(24, 24, 4), 256, 0, stream>>>(Wq, Wk, Wv, Wo, wt);
  k_bias3<<<dim3(9), 256, 0, stream>>>(bq, bk, bv, bqkv);
  // 2. gate
  k_pool1<<<dim3(8, NB_), 256, 0, stream>>>(hs, mask, partial, pcnt);
  k_pool2<<<dim3(NB_), 256, 0, stream>>>(partial, pcnt, Wg, bg, gate);
  // 3. fused QKV projection: [8192x768] x [2304x768]^T -> [8192][2304]
  k_gemm_bt<1, 0, 0, 0><<<dim3(18, 64, 1), 256, 0, stream>>>(
      hsb, 0, D_, wt, 0, D_, qkvb, 0, 3 * D_, bqkv, nullptr, 1.0f, D_);
  // 4. V transpose per head (v at col 1536 of qkvb)
  k_vtrans<<<dim3(S_ / 64, NB_ * H_), 256, 0, stream>>>(qkvb + 2 * D_, 3 * D_, vtb);
  // 5. priorctx = prior @ V  (per batch: fp32 prior [512x512] x vt[b]^T([768x512]) -> [512][768])
  k_gemm_bt<1, 0, 0, 1><<<dim3(6, 4, NB_), 256, 0, stream>>>(
      prior, (long)S_ * S_, S_, vtb, (long)H_ * DH_ * S_, S_,
      priorctx, (long)S_ * D_, D_, nullptr, nullptr, 1.0f, S_);
  // 6. flash attention + prior blend -> ctx (bf16)
  k_flash<<<dim3(S_ / QT_, 1, NB_ * H_), 256, 0, stream>>>(
      qkvb, vtb, priorctx, mask, gate, ctx);
  // 7. out = relu(ctx·Wo + bo) + hs  (fp32 into d_out)
  k_gemm_bt<0, 1, 1, 0><<<dim3(6, 64, 1), 256, 0, stream>>>(
      ctx, 0, D_, wt + 3 * (size_t)D_ * D_, 0, D_, out, 0, D_, bo, hs, 1.0f, D_);
  // 8. LayerNorm in place on d_out
  k_ln<<<dim3(NB_ * S_), 256, 0, stream>>>(out, gamma, beta);
}

// Round 6
// 319.559 us; speedup vs baseline: 1.0212x; 1.0212x over previous
//
#include <hip/hip_runtime.h>

#define NB_ 16   // batch
#define S_ 512
#define D_ 768
#define H_ 12
#define DH_ 64
#define QT_ 64   // flash q-tile
#define KT_ 128  // flash k-tile

typedef __attribute__((ext_vector_type(8))) short bf16x8;
typedef __attribute__((ext_vector_type(4))) float f32x4;
typedef unsigned short ushort_t;

__device__ __forceinline__ unsigned short f2bf(float f){
  unsigned int u = __float_as_uint(f);
  u += 0x7fffu + ((u >> 16) & 1u);   // round-to-nearest-even
  return (unsigned short)(u >> 16);
}
__device__ __forceinline__ float bf2f(unsigned short s){
  return __uint_as_float(((unsigned int)s) << 16);
}
// async global->LDS, 16B per lane. LDS side must be uniform-base + lane*16,
// which holds because chunk index is linear in tid within each wave.
__device__ __forceinline__ void gld16(const ushort_t* g, ushort_t* l){
  __builtin_amdgcn_global_load_lds((const __attribute__((address_space(1))) unsigned int*)g,
                                   (__attribute__((address_space(3))) unsigned int*)l, 16, 0, 0);
}

// ---------------- weight transpose fp32[K][N] -> bf16[N][K] ----------------
__global__ __launch_bounds__(256) void k_wtrans(const float* __restrict__ W0, const float* __restrict__ W1,
                                                const float* __restrict__ W2, const float* __restrict__ W3,
                                                ushort_t* __restrict__ dst){
  const float* W = (blockIdx.z == 0) ? W0 : (blockIdx.z == 1) ? W1 : (blockIdx.z == 2) ? W2 : W3;
  ushort_t* o = dst + (size_t)blockIdx.z * D_ * D_;
  __shared__ float t[32][33];
  int j = threadIdx.x & 31, i0 = threadIdx.x >> 5;
  int kb = blockIdx.y * 32, nb = blockIdx.x * 32;
#pragma unroll
  for (int r = 0; r < 4; r++){
    int i = i0 + r * 8;
    t[i][j] = W[(size_t)(kb + i) * D_ + nb + j];
  }
  __syncthreads();
#pragma unroll
  for (int r = 0; r < 4; r++){
    int i = i0 + r * 8;
    o[(size_t)(nb + i) * D_ + kb + j] = f2bf(t[j][i]);
  }
}

// ---------------- concat bq|bk|bv -> [2304] ----------------
__global__ __launch_bounds__(256) void k_bias3(const float* __restrict__ b0, const float* __restrict__ b1,
                                               const float* __restrict__ b2, float* __restrict__ o){
  int i = blockIdx.x * 256 + threadIdx.x;
  if (i < 3 * D_){
    float v = (i < D_) ? b0[i] : (i < 2 * D_) ? b1[i - D_] : b2[i - 2 * D_];
    o[i] = v;
  }
}

// ---------------- fused hs->bf16 convert + pooled-gate stage 1 ----------------
// grid (8, B): converts 64 rows to bf16 AND accumulates masked partial sums.
__global__ __launch_bounds__(256) void k_prep(const float* __restrict__ hs, const float* __restrict__ mask,
                                              ushort_t* __restrict__ hsb,
                                              float* __restrict__ partial, float* __restrict__ pcnt){
  int chunk = blockIdx.x, b = blockIdx.y, tid = threadIdx.x;
  const float* mrow = mask + b * S_ + chunk * 64;
  const float* base = hs + ((size_t)b * S_ + chunk * 64) * D_;
  ushort_t* obase = hsb + ((size_t)b * S_ + chunk * 64) * D_;
  float a0 = 0.f, a1 = 0.f, a2 = 0.f, cnt = 0.f;
#pragma unroll 2
  for (int s = 0; s < 64; s++){
    const float* r = base + (size_t)s * D_;
    float x0 = r[tid], x1 = r[tid + 256], x2 = r[tid + 512];
    ushort_t* o = obase + (size_t)s * D_;
    o[tid] = f2bf(x0); o[tid + 256] = f2bf(x1); o[tid + 512] = f2bf(x2);
    if (mrow[s] == 0.0f){ a0 += x0; a1 += x1; a2 += x2; cnt += 1.0f; }
  }
  float* o = partial + (size_t)(b * 8 + chunk) * D_;
  o[tid] = a0; o[tid + 256] = a1; o[tid + 512] = a2;
  if (tid == 0) pcnt[b * 8 + chunk] = cnt;
}

// ---------------- pooled gate, stage 2 ----------------
__global__ __launch_bounds__(256) void k_pool2(const float* __restrict__ partial, const float* __restrict__ pcnt,
                                               const float* __restrict__ Wg, const float* __restrict__ bg,
                                               float* __restrict__ gate){
  int b = blockIdx.x, tid = threadIdx.x;
  __shared__ float red[256];
  __shared__ float hp[768];
  float a0 = 0.f, a1 = 0.f, a2 = 0.f;
#pragma unroll
  for (int c = 0; c < 8; c++){
    const float* p = partial + (size_t)(b * 8 + c) * D_;
    a0 += p[tid]; a1 += p[tid + 256]; a2 += p[tid + 512];
  }
  float denom = 0.f;
#pragma unroll
  for (int c = 0; c < 8; c++) denom += pcnt[b * 8 + c];
  float inv = 1.0f / fmaxf(denom, 1.0f);
  hp[tid] = a0 * inv; hp[tid + 256] = a1 * inv; hp[tid + 512] = a2 * inv;
  __syncthreads();
  float p0 = 0.f, p1 = 0.f;
  for (int d = tid; d < D_; d += 256){ p0 += hp[d] * Wg[d * 2]; p1 += hp[d] * Wg[d * 2 + 1]; }
  red[tid] = p0; __syncthreads();
  for (int o = 128; o > 0; o >>= 1){ if (tid < o) red[tid] += red[tid + o]; __syncthreads(); }
  float z0 = red[0]; __syncthreads();
  red[tid] = p1; __syncthreads();
  for (int o = 128; o > 0; o >>= 1){ if (tid < o) red[tid] += red[tid + o]; __syncthreads(); }
  float z1 = red[0];
  if (tid == 0){
    z0 = (z0 + bg[0]) * 0.5f; z1 = (z1 + bg[1]) * 0.5f;
    float m = fmaxf(z0, z1);
    float e0 = __expf(z0 - m), e1 = __expf(z1 - m);
    float ssum = e0 + e1;
    gate[b * 2] = e0 / ssum; gate[b * 2 + 1] = e1 / ssum;
  }
}

// ---------------- BT GEMM (128x128 tile, BK=64, swizzled LDS, global_load_lds) ----------
// C[z] = act(alpha*A[z]*B[z]^T + bias [+ resid]); A:[M][K] lda, B:[N][K] ldb.
// LDS: 8 16B-chunks per row; chunk c of row r stored at r*8 + (c ^ (r&7)).
// Staging lane-linear (gld16-legal); fragment reads spread across all banks.
// AFP32: A operand fp32 in global, converted to bf16 during staging (VGPR path).
template<int OUTBF16, int RELU, int RESID, int AFP32>
__global__ __launch_bounds__(256) void k_gemm_bt(
    const void* __restrict__ Ap, long sA, int lda,
    const ushort_t* __restrict__ Bm, long sB, int ldb,
    void* __restrict__ Cp, long sC, int ldc,
    const float* __restrict__ bias,
    const float* __restrict__ resid, float alpha, int K)
{
  __shared__ ushort_t As[128 * 64];
  __shared__ ushort_t Bs[128 * 64];
  const int z = blockIdx.z;
  const ushort_t* Ab = AFP32 ? nullptr : ((const ushort_t*)Ap + (size_t)z * sA);
  const float*    Af = AFP32 ? ((const float*)Ap + (size_t)z * sA) : nullptr;
  const ushort_t* Bb = Bm + (size_t)z * sB;
  const long coff = (long)z * sC;
  const int tid = threadIdx.x;
  const int m0 = blockIdx.y * 128, n0 = blockIdx.x * 128;
  const int wid = tid >> 6, lane = tid & 63;
  const int quad = lane >> 4, l16 = lane & 15;
  const int wm = wid >> 1, wn = wid & 1;
  const int sw = l16 & 7;                 // fragment-read swizzle (row-local)

  f32x4 acc[4][4];
#pragma unroll
  for (int i = 0; i < 4; i++)
#pragma unroll
    for (int j = 0; j < 4; j++) acc[i][j] = (f32x4){0.f, 0.f, 0.f, 0.f};

  for (int k0 = 0; k0 < K; k0 += 64){
#pragma unroll
    for (int c = 0; c < 4; c++){
      int idx = tid + c * 256;            // 1024 chunks: row = idx>>3, pos = idx&7
      int row = idx >> 3, p = idx & 7;
      int cg = p ^ (row & 7);
      if (AFP32){
        const float* src = Af + (size_t)(m0 + row) * lda + k0 + cg * 8;
        float4 f0 = *(const float4*)src;
        float4 f1 = *(const float4*)(src + 4);
        uint4 pk;
        pk.x = (unsigned int)f2bf(f0.x) | ((unsigned int)f2bf(f0.y) << 16);
        pk.y = (unsigned int)f2bf(f0.z) | ((unsigned int)f2bf(f0.w) << 16);
        pk.z = (unsigned int)f2bf(f1.x) | ((unsigned int)f2bf(f1.y) << 16);
        pk.w = (unsigned int)f2bf(f1.z) | ((unsigned int)f2bf(f1.w) << 16);
        *(uint4*)(&As[idx * 8]) = pk;
      } else {
        gld16(Ab + (size_t)(m0 + row) * lda + k0 + cg * 8, &As[idx * 8]);
      }
    }
#pragma unroll
    for (int c = 0; c < 4; c++){
      int idx = tid + c * 256;
      int row = idx >> 3, p = idx & 7;
      int cg = p ^ (row & 7);
      gld16(Bb + (size_t)(n0 + row) * ldb + k0 + cg * 8, &Bs[idx * 8]);
    }
    __syncthreads();
#pragma unroll
    for (int ks = 0; ks < 2; ks++){
      bf16x8 af[4], bfv[4];
#pragma unroll
      for (int mi = 0; mi < 4; mi++){
        int row = wm * 64 + mi * 16 + l16;
        af[mi] = *(const bf16x8*)(&As[(row * 8 + ((ks * 4 + quad) ^ sw)) * 8]);
      }
#pragma unroll
      for (int ni = 0; ni < 4; ni++){
        int row = wn * 64 + ni * 16 + l16;
        bfv[ni] = *(const bf16x8*)(&Bs[(row * 8 + ((ks * 4 + quad) ^ sw)) * 8]);
      }
#pragma unroll
      for (int mi = 0; mi < 4; mi++)
#pragma unroll
        for (int ni = 0; ni < 4; ni++)
          acc[mi][ni] = __builtin_amdgcn_mfma_f32_16x16x32_bf16(af[mi], bfv[ni], acc[mi][ni], 0, 0, 0);
    }
    __syncthreads();
  }

#pragma unroll
  for (int mi = 0; mi < 4; mi++){
#pragma unroll
    for (int ni = 0; ni < 4; ni++){
      int col = n0 + wn * 64 + ni * 16 + l16;
      float bcol = bias ? bias[col] : 0.0f;
#pragma unroll
      for (int r = 0; r < 4; r++){
        int row = m0 + wm * 64 + mi * 16 + quad * 4 + r;
        float v = acc[mi][ni][r] * alpha + bcol;
        if (RELU) v = fmaxf(v, 0.0f);
        if (RESID) v += resid[(size_t)row * ldc + col];
        long idx = coff + (long)row * ldc + col;
        if (OUTBF16) ((ushort_t*)Cp)[idx] = f2bf(v);
        else         ((float*)Cp)[idx] = v;
      }
    }
  }
}

// ---------------- per-head V transpose: vt[z][dh][t] = v[b,t,(voff)+h*64+dh] ----------------
__global__ __launch_bounds__(256) void k_vtrans(const ushort_t* __restrict__ v, int ldv,
                                                ushort_t* __restrict__ vt){
  __shared__ ushort_t t[64][66];
  int st = blockIdx.x * 64; int z = blockIdx.y;
  int b = z / H_, h = z - b * H_;
  int tid = threadIdx.x;
  const ushort_t* src = v + ((size_t)b * S_ + st) * ldv + h * DH_;
#pragma unroll
  for (int rep = 0; rep < 8; rep++){
    int idx = rep * 256 + tid;
    int i = idx >> 5, u = idx & 31;
    unsigned int val = *(const unsigned int*)(src + (size_t)i * ldv + u * 2);
    *(unsigned int*)(&t[i][u * 2]) = val;
  }
  __syncthreads();
  ushort_t* dst = vt + (size_t)z * DH_ * S_ + st;
#pragma unroll
  for (int rep = 0; rep < 8; rep++){
    int idx = rep * 256 + tid;
    int d = idx >> 5, u2 = idx & 31;
    unsigned int val = (unsigned int)t[u2 * 2][d] | ((unsigned int)t[u2 * 2 + 1][d] << 16);
    *(unsigned int*)(dst + (size_t)d * S_ + u2 * 2) = val;
  }
}

// ---------------- fused flash attention with prior blend ----------------
// ctx[b,q,h*64+dh] = (g0/l_q) * sum_t exp(0.125*q.k + mask_t) * V[t,dh] + g1 * priorctx[b,q,h*64+dh]
__global__ __launch_bounds__(256) void k_flash(
    const ushort_t* __restrict__ qkv,      // [B*S][2304]; q at col 0, k at col 768
    const ushort_t* __restrict__ vt,       // [B*H][64][512]
    const ushort_t* __restrict__ priorctx, // [B*S][768] bf16
    const float* __restrict__ mask,        // [B][S]
    const float* __restrict__ gate,        // [B][2]
    ushort_t* __restrict__ ctx)            // [B*S][768]
{
  __shared__ ushort_t Qs[QT_ * 72];    // [q][dh], pad to 72
  __shared__ ushort_t Ks[KT_ * 72];    // [t][dh]
  __shared__ ushort_t Vs[DH_ * 136];   // [dh][t], pad to 136
  __shared__ ushort_t Ps[QT_ * 136];   // [q][t]
  __shared__ float rs[QT_];
  const int z = blockIdx.z, b = z / H_, h = z - b * H_;
  const int q0 = blockIdx.x * QT_;
  const int tid = threadIdx.x;
  const int wid = tid >> 6, lane = tid & 63, quad = lane >> 4, l16 = lane & 15;

  // stage Q tile (64 x 64)
#pragma unroll
  for (int i = 0; i < 2; i++){
    int c = tid + i * 256;
    int row = c >> 3, off = (c & 7) * 8;
    *(float4*)(&Qs[row * 72 + off]) =
      *(const float4*)(qkv + ((size_t)(b * S_ + q0 + row)) * 2304 + h * DH_ + off);
  }
  if (tid < QT_) rs[tid] = 0.f;

  f32x4 accv[4];
#pragma unroll
  for (int ni = 0; ni < 4; ni++) accv[ni] = (f32x4){0.f, 0.f, 0.f, 0.f};

  for (int t0 = 0; t0 < S_; t0 += KT_){
    // stage K tile (128 x 64) and V^T tile (64 x 128)
#pragma unroll
    for (int i = 0; i < 4; i++){
      int c = tid + i * 256;
      int row = c >> 3, off = (c & 7) * 8;
      *(float4*)(&Ks[row * 72 + off]) =
        *(const float4*)(qkv + ((size_t)(b * S_ + t0 + row)) * 2304 + D_ + h * DH_ + off);
    }
#pragma unroll
    for (int i = 0; i < 4; i++){
      int c = tid + i * 256;
      int row = c >> 4, off = (c & 15) * 8;
      *(float4*)(&Vs[row * 136 + off]) =
        *(const float4*)(vt + (size_t)z * (DH_ * S_) + (size_t)row * S_ + t0 + off);
    }
    __syncthreads();

    // S^T = K·Q^T : A = K tokens (m, 128), B = Q rows (n, 64), k-dim = dh (64)
    f32x4 accs[2][4];
#pragma unroll
    for (int mi = 0; mi < 2; mi++)
#pragma unroll
      for (int ni = 0; ni < 4; ni++) accs[mi][ni] = (f32x4){0.f, 0.f, 0.f, 0.f};
    bf16x8 ak[2][2], bq[4][2];
#pragma unroll
    for (int mi = 0; mi < 2; mi++)
#pragma unroll
      for (int ks = 0; ks < 2; ks++)
        ak[mi][ks] = *(const bf16x8*)(&Ks[(wid * 32 + mi * 16 + l16) * 72 + ks * 32 + quad * 8]);
#pragma unroll
    for (int ni = 0; ni < 4; ni++)
#pragma unroll
      for (int ks = 0; ks < 2; ks++)
        bq[ni][ks] = *(const bf16x8*)(&Qs[(ni * 16 + l16) * 72 + ks * 32 + quad * 8]);
#pragma unroll
    for (int mi = 0; mi < 2; mi++)
#pragma unroll
      for (int ni = 0; ni < 4; ni++){
        accs[mi][ni] = __builtin_amdgcn_mfma_f32_16x16x32_bf16(ak[mi][0], bq[ni][0], accs[mi][ni], 0, 0, 0);
        accs[mi][ni] = __builtin_amdgcn_mfma_f32_16x16x32_bf16(ak[mi][1], bq[ni][1], accs[mi][ni], 0, 0, 0);
      }

    // exp + pack into Ps[q][t] (lane holds 4 contiguous t for fixed q) + row sums
    float mv[2][4];
#pragma unroll
    for (int mi = 0; mi < 2; mi++)
#pragma unroll
      for (int r = 0; r < 4; r++)
        mv[mi][r] = mask[b * S_ + t0 + wid * 32 + mi * 16 + quad * 4 + r];
    float rowpart[4] = {0.f, 0.f, 0.f, 0.f};
#pragma unroll
    for (int mi = 0; mi < 2; mi++){
#pragma unroll
      for (int ni = 0; ni < 4; ni++){
        float e0 = __expf(accs[mi][ni][0] * 0.125f + mv[mi][0]);
        float e1 = __expf(accs[mi][ni][1] * 0.125f + mv[mi][1]);
        float e2 = __expf(accs[mi][ni][2] * 0.125f + mv[mi][2]);
        float e3 = __expf(accs[mi][ni][3] * 0.125f + mv[mi][3]);
        rowpart[ni] += (e0 + e1) + (e2 + e3);
        uint2 pk;
        pk.x = (unsigned int)f2bf(e0) | ((unsigned int)f2bf(e1) << 16);
        pk.y = (unsigned int)f2bf(e2) | ((unsigned int)f2bf(e3) << 16);
        *(uint2*)(&Ps[(ni * 16 + l16) * 136 + wid * 32 + mi * 16 + quad * 4]) = pk;
      }
    }
#pragma unroll
    for (int ni = 0; ni < 4; ni++){
      rowpart[ni] += __shfl_xor(rowpart[ni], 16);
      rowpart[ni] += __shfl_xor(rowpart[ni], 32);
    }
    if (lane < 16){
#pragma unroll
      for (int ni = 0; ni < 4; ni++) atomicAdd(&rs[ni * 16 + l16], rowpart[ni]);
    }
    __syncthreads();

    // PV: A = Ps (m = q, this wave's 16 rows), B = Vs (n = dh), k = t (128)
#pragma unroll
    for (int ks = 0; ks < 4; ks++){
      bf16x8 ap = *(const bf16x8*)(&Ps[(wid * 16 + l16) * 136 + ks * 32 + quad * 8]);
#pragma unroll
      for (int ni = 0; ni < 4; ni++){
        bf16x8 bv8 = *(const bf16x8*)(&Vs[(ni * 16 + l16) * 136 + ks * 32 + quad * 8]);
        accv[ni] = __builtin_amdgcn_mfma_f32_16x16x32_bf16(ap, bv8, accv[ni], 0, 0, 0);
      }
    }
    __syncthreads();
  }

  const float g0 = gate[b * 2], g1 = gate[b * 2 + 1];
#pragma unroll
  for (int ni = 0; ni < 4; ni++){
#pragma unroll
    for (int r = 0; r < 4; r++){
      int q = wid * 16 + quad * 4 + r;
      int dh = ni * 16 + l16;
      float scl = g0 / rs[q];
      size_t idx = ((size_t)(b * S_ + q0 + q)) * D_ + h * DH_ + dh;
      float v = accv[ni][r] * scl + g1 * bf2f(priorctx[idx]);
      ctx[idx] = f2bf(v);
    }
  }
}

// ---------------- in-place LayerNorm over D=768 ----------------
__global__ __launch_bounds__(256) void k_ln(float* __restrict__ out, const float* __restrict__ gamma,
                                            const float* __restrict__ beta){
  __shared__ float red[256];
  int row = blockIdx.x, tid = threadIdx.x;
  float* p = out + (size_t)row * D_;
  float x0 = p[tid], x1 = p[tid + 256], x2 = p[tid + 512];
  red[tid] = x0 + x1 + x2; __syncthreads();
  for (int o = 128; o > 0; o >>= 1){ if (tid < o) red[tid] += red[tid + o]; __syncthreads(); }
  float mu = red[0] * (1.0f / 768.0f);
  __syncthreads();
  float d0 = x0 - mu, d1 = x1 - mu, d2 = x2 - mu;
  red[tid] = d0 * d0 + d1 * d1 + d2 * d2; __syncthreads();
  for (int o = 128; o > 0; o >>= 1){ if (tid < o) red[tid] += red[tid + o]; __syncthreads(); }
  float rsv = rsqrtf(red[0] * (1.0f / 768.0f) + 1e-5f);
  p[tid]       = d0 * rsv * gamma[tid]       + beta[tid];
  p[tid + 256] = d1 * rsv * gamma[tid + 256] + beta[tid + 256];
  p[tid + 512] = d2 * rsv * gamma[tid + 512] + beta[tid + 512];
}

extern "C" void kernel_launch(void* const* d_in, const int* in_sizes, int n_in,
                              void* d_out, int out_size, void* d_ws, size_t ws_size,
                              hipStream_t stream){
  const float* hs    = (const float*)d_in[0];
  const float* mask  = (const float*)d_in[1];
  const float* prior = (const float*)d_in[2];
  const float* Wq = (const float*)d_in[3];  const float* bq = (const float*)d_in[4];
  const float* Wk = (const float*)d_in[5];  const float* bk = (const float*)d_in[6];
  const float* Wv = (const float*)d_in[7];  const float* bv = (const float*)d_in[8];
  const float* Wg = (const float*)d_in[9];  const float* bg = (const float*)d_in[10];
  const float* Wo = (const float*)d_in[11]; const float* bo = (const float*)d_in[12];
  const float* gamma = (const float*)d_in[13]; const float* beta = (const float*)d_in[14];
  float* out = (float*)d_out;

  size_t off = 0;
  auto alloc = [&](size_t bytes) -> char* {
    char* p = (char*)d_ws + off;
    off += (bytes + 255) & ~(size_t)255;
    return p;
  };
  const size_t HSD = (size_t)NB_ * S_ * D_;            // 6.29M elems
  ushort_t* hsb     = (ushort_t*)alloc(HSD * 2);
  ushort_t* qkvb    = (ushort_t*)alloc(HSD * 3 * 2);   // [B*S][2304]
  ushort_t* vtb     = (ushort_t*)alloc(HSD * 2);       // [B*H][64][512]
  ushort_t* wt      = (ushort_t*)alloc((size_t)4 * D_ * D_ * 2);
  ushort_t* priorctx= (ushort_t*)alloc(HSD * 2);
  ushort_t* ctx     = (ushort_t*)alloc(HSD * 2);
  float*    bqkv    = (float*)alloc((size_t)3 * D_ * 4);
  float*    gate    = (float*)alloc(256);
  float*    partial = (float*)alloc((size_t)NB_ * 8 * D_ * 4);
  float*    pcnt    = (float*)alloc((size_t)NB_ * 8 * 4);

  // 1. converts / packs (hs convert fused with pool stage-1)
  k_prep<<<dim3(8, NB_), 256, 0, stream>>>(hs, mask, hsb, partial, pcnt);
  k_wtrans<<<dim3(24, 24, 4), 256, 0, stream>>>(Wq, Wk, Wv, Wo, wt);
  k_bias3<<<dim3(9), 256, 0, stream>>>(bq, bk, bv, bqkv);
  // 2. gate
  k_pool2<<<dim3(NB_), 256, 0, stream>>>(partial, pcnt, Wg, bg, gate);
  // 3. fused QKV projection: [8192x768] x [2304x768]^T -> [8192][2304]
  k_gemm_bt<1, 0, 0, 0><<<dim3(18, 64, 1), 256, 0, stream>>>(
      hsb, 0, D_, wt, 0, D_, qkvb, 0, 3 * D_, bqkv, nullptr, 1.0f, D_);
  // 4. V transpose per head (v at col 1536 of qkvb)
  k_vtrans<<<dim3(S_ / 64, NB_ * H_), 256, 0, stream>>>(qkvb + 2 * D_, 3 * D_, vtb);
  // 5. priorctx = prior @ V  (per batch: fp32 prior [512x512] x vt[b]^T([768x512]) -> [512][768])
  k_gemm_bt<1, 0, 0, 1><<<dim3(6, 4, NB_), 256, 0, stream>>>(
      prior, (long)S_ * S_, S_, vtb, (long)H_ * DH_ * S_, S_,
      priorctx, (long)S_ * D_, D_, nullptr, nullptr, 1.0f, S_);
  // 6. flash attention + prior blend -> ctx (bf16)
  k_flash<<<dim3(S_ / QT_, 1, NB_ * H_), 256, 0, stream>>>(
      qkvb, vtb, priorctx, mask, gate, ctx);
  // 7. out = relu(ctx·Wo + bo) + hs  (fp32 into d_out)
  k_gemm_bt<0, 1, 1, 0><<<dim3(6, 64, 1), 256, 0, stream>>>(
      ctx, 0, D_, wt + 3 * (size_t)D_ * D_, 0, D_, out, 0, D_, bo, hs, 1.0f, D_);
  // 8. LayerNorm in place on d_out
  k_ln<<<dim3(NB_ * S_), 256, 0, stream>>>(out, gamma, beta);
}